// Round 3
// baseline (3216.758 us; speedup 1.0000x reference)
//
#include <hip/hip_runtime.h>
#include <hip/hip_bf16.h>
#include <math.h>

#define G_GRAPHS 8

// ---------- helpers ----------
__device__ __forceinline__ unsigned fmap(float f) {
    unsigned b = __float_as_uint(f);
    return (b & 0x80000000u) ? ~b : (b | 0x80000000u);
}
__device__ __forceinline__ float funmap(unsigned u) {
    unsigned b = (u & 0x80000000u) ? (u & 0x7fffffffu) : ~u;
    return __uint_as_float(b);
}

// ---------- CSR build ----------
__global__ void k_count(const int* __restrict__ dst, int* __restrict__ deg, int E) {
    int e = blockIdx.x * 256 + threadIdx.x;
    if (e < E) atomicAdd(&deg[dst[e]], 1);
}

__global__ void k_dis(const int* __restrict__ deg, float* __restrict__ dis, int N) {
    int i = blockIdx.x * 256 + threadIdx.x;
    if (i < N) dis[i] = rsqrtf((float)(deg[i] + 1));  // +1 = self loop
}

__global__ void k_scanA(const int* __restrict__ deg, int* __restrict__ rowst,
                        int* __restrict__ bsum, int N) {
    __shared__ int s[256];
    int i = blockIdx.x * 256 + threadIdx.x;
    int v = (i < N) ? deg[i] : 0;
    s[threadIdx.x] = v;
    __syncthreads();
    for (int off = 1; off < 256; off <<= 1) {
        int t = (threadIdx.x >= off) ? s[threadIdx.x - off] : 0;
        __syncthreads();
        s[threadIdx.x] += t;
        __syncthreads();
    }
    if (i < N) rowst[i] = s[threadIdx.x] - v;   // block-local exclusive
    if (threadIdx.x == 255) bsum[blockIdx.x] = s[255];
}

__global__ void k_scanB(int* __restrict__ bsum, int NB) {
    __shared__ int s[512];
    int t = threadIdx.x;
    int v = (t < NB) ? bsum[t] : 0;
    s[t] = v;
    __syncthreads();
    for (int off = 1; off < 512; off <<= 1) {
        int x = (t >= off) ? s[t - off] : 0;
        __syncthreads();
        s[t] += x;
        __syncthreads();
    }
    if (t < NB) bsum[t] = s[t] - v;             // exclusive
}

__global__ void k_scanC(int* __restrict__ rowst, const int* __restrict__ bsum, int N) {
    int i = blockIdx.x * 256 + threadIdx.x;
    if (i < N) rowst[i] += bsum[blockIdx.x];
}

__global__ void k_fill(const int* __restrict__ src, const int* __restrict__ dst,
                       const float* __restrict__ dis, const int* __restrict__ rowst,
                       int* __restrict__ cnt, int* __restrict__ col,
                       float* __restrict__ wgt, int E) {
    int e = blockIdx.x * 256 + threadIdx.x;
    if (e >= E) return;
    int d = dst[e], s = src[e];
    int p = rowst[d] + atomicAdd(&cnt[d], 1);
    col[p] = s;
    wgt[p] = dis[s] * dis[d];
}

// ---------- encoder: out = relu(prop(x)@W1+b1)@W2  ----------
__global__ __launch_bounds__(256) void k_enc(
        const float* __restrict__ x, float* __restrict__ out,
        const float* __restrict__ dis, const int* __restrict__ rowst,
        const int* __restrict__ deg, const int* __restrict__ col,
        const float* __restrict__ wgt,
        const float* __restrict__ W1, const float* __restrict__ b1,
        const float* __restrict__ W2, int N) {
    __shared__ float prow[4][16];
    __shared__ float4 z1T[128];   // z1T[k] = {node0..3}[feature k]
    int t = threadIdx.x, lane = t & 63, w = t >> 6;
    int qq = lane & 3, e = lane >> 2;          // 16 edge groups x 4 lanes (float4)
    int node = blockIdx.x * 4 + w;
    bool valid = node < N;
    if (valid) {
        const float4* x4 = (const float4*)x;
        float d = dis[node];
        float sc = d * d * (1.f / 16.f);       // self-loop spread over 16 groups
        float4 sf = x4[node * 4 + qq];
        float ax = sf.x * sc, ay = sf.y * sc, az = sf.z * sc, aw = sf.w * sc;
        int s = rowst[node], dg = deg[node];
        for (int i = e; i < dg; i += 16) {
            int c = col[s + i];
            float wv = wgt[s + i];
            float4 r = x4[c * 4 + qq];
            ax += wv * r.x; ay += wv * r.y; az += wv * r.z; aw += wv * r.w;
        }
        ax += __shfl_xor(ax, 4);  ay += __shfl_xor(ay, 4);  az += __shfl_xor(az, 4);  aw += __shfl_xor(aw, 4);
        ax += __shfl_xor(ax, 8);  ay += __shfl_xor(ay, 8);  az += __shfl_xor(az, 8);  aw += __shfl_xor(aw, 8);
        ax += __shfl_xor(ax, 16); ay += __shfl_xor(ay, 16); az += __shfl_xor(az, 16); aw += __shfl_xor(aw, 16);
        ax += __shfl_xor(ax, 32); ay += __shfl_xor(ay, 32); az += __shfl_xor(az, 32); aw += __shfl_xor(aw, 32);
        if (lane < 4)
            ((float4*)prow[w])[lane] = make_float4(ax, ay, az, aw);
        // z1 = relu(p@W1+b1): lane produces features lane, lane+64
        float a0 = b1[lane], a1 = b1[lane + 64];
        for (int k = 0; k < 16; ++k) {
            float p = prow[w][k];
            a0 += p * W1[k * 128 + lane];
            a1 += p * W1[k * 128 + lane + 64];
        }
        ((float*)&z1T[lane])[w]      = fmaxf(a0, 0.f);
        ((float*)&z1T[lane + 64])[w] = fmaxf(a1, 0.f);
    } else {
        ((float*)&z1T[lane])[w]      = 0.f;
        ((float*)&z1T[lane + 64])[w] = 0.f;
    }
    __syncthreads();
    if (w == 0) {   // one wave: y2 = z1@W2 for all 4 nodes (4 acc/lane)
        int base = blockIdx.x * 4;
        const float* W2l = W2 + lane;
        float a0 = 0.f, a1 = 0.f, a2 = 0.f, a3 = 0.f;
        for (int k = 0; k < 128; ++k) {
            float wk = W2l[k * 64];
            float4 z = z1T[k];
            a0 += z.x * wk; a1 += z.y * wk; a2 += z.z * wk; a3 += z.w * wk;
        }
        if (base + 0 < N) out[(base + 0) * 64 + lane] = a0;
        if (base + 1 < N) out[(base + 1) * 64 + lane] = a1;
        if (base + 2 < N) out[(base + 2) * 64 + lane] = a2;
        if (base + 3 < N) out[(base + 3) * 64 + lane] = a3;
    }
}

// ---------- prop64: z = prop(in)+bias [relu]; out = W ? z@W (+gbias) : z ----------
// wave per node, lane = feature; 8-deep software-pipelined gather
__global__ __launch_bounds__(256) void k_prop64(
        const float* __restrict__ in, float* __restrict__ out,
        const float* __restrict__ dis, const int* __restrict__ rowst,
        const int* __restrict__ deg, const int* __restrict__ col,
        const float* __restrict__ wgt,
        const float* __restrict__ bias, int relu,
        const float* __restrict__ W, const float* __restrict__ gbias, int N) {
    __shared__ float4 rowT[64];    // rowT[k] = {node0..3}[feature k]
    int lane = threadIdx.x & 63, w = threadIdx.x >> 6;
    int node = blockIdx.x * 4 + w;
    bool valid = node < N;
    float acc = 0.f;
    if (valid) {
        const float* inl = in + lane;
        float d = dis[node];
        acc = inl[node * 64] * (d * d);
        int s = rowst[node], dg = deg[node];
        const int* cp = col + s;
        const float* wp = wgt + s;
        int i = 0;
        for (; i + 8 <= dg; i += 8) {
            int c0 = cp[i+0], c1 = cp[i+1], c2 = cp[i+2], c3 = cp[i+3];
            int c4 = cp[i+4], c5 = cp[i+5], c6 = cp[i+6], c7 = cp[i+7];
            float w0 = wp[i+0], w1 = wp[i+1], w2 = wp[i+2], w3 = wp[i+3];
            float w4 = wp[i+4], w5 = wp[i+5], w6 = wp[i+6], w7 = wp[i+7];
            float v0 = inl[c0*64], v1 = inl[c1*64], v2 = inl[c2*64], v3 = inl[c3*64];
            float v4 = inl[c4*64], v5 = inl[c5*64], v6 = inl[c6*64], v7 = inl[c7*64];
            acc += w0*v0; acc += w1*v1; acc += w2*v2; acc += w3*v3;
            acc += w4*v4; acc += w5*v5; acc += w6*v6; acc += w7*v7;
        }
        if (i + 4 <= dg) {
            int c0 = cp[i+0], c1 = cp[i+1], c2 = cp[i+2], c3 = cp[i+3];
            float w0 = wp[i+0], w1 = wp[i+1], w2 = wp[i+2], w3 = wp[i+3];
            float v0 = inl[c0*64], v1 = inl[c1*64], v2 = inl[c2*64], v3 = inl[c3*64];
            acc += w0*v0; acc += w1*v1; acc += w2*v2; acc += w3*v3;
            i += 4;
        }
        for (; i < dg; ++i) acc += wp[i] * inl[cp[i]*64];
        if (bias) acc += bias[lane];
        if (relu) acc = fmaxf(acc, 0.f);
    }
    if (!W) {
        if (valid) out[node * 64 + lane] = acc;
        return;
    }
    ((float*)&rowT[lane])[w] = acc;
    __syncthreads();
    if (w == 0) {   // one wave: z@W for all 4 nodes
        int base = blockIdx.x * 4;
        const float* Wl = W + lane;
        float b = gbias ? gbias[lane] : 0.f;
        float a0 = b, a1 = b, a2 = b, a3 = b;
        for (int k = 0; k < 64; ++k) {
            float wk = Wl[k * 64];
            float4 z = rowT[k];
            a0 += z.x * wk; a1 += z.y * wk; a2 += z.z * wk; a3 += z.w * wk;
        }
        if (base + 0 < N) out[(base + 0) * 64 + lane] = a0;
        if (base + 1 < N) out[(base + 1) * 64 + lane] = a1;
        if (base + 2 < N) out[(base + 2) * 64 + lane] = a2;
        if (base + 3 < N) out[(base + 3) * 64 + lane] = a3;
    }
}

// ---------- pooling + head ----------
__global__ void k_pool_init(unsigned* __restrict__ gmax) {
    gmax[blockIdx.x * 64 + threadIdx.x] = fmap(-INFINITY);
}

__global__ void k_pool(const float* __restrict__ z, const int* __restrict__ batch,
                       unsigned* __restrict__ gmax, int N) {
    int f = threadIdx.x & 63, w = threadIdx.x >> 6;
    int base = (blockIdx.x * 4 + w) * 32;
    if (base >= N) return;
    int end = base + 32; if (end > N) end = N;
    int b0 = batch[base], b1 = batch[end - 1];
    if (b0 == b1) {                            // fast path: single graph in window
        float lmax = -INFINITY;
        for (int n = base; n < end; ++n)
            lmax = fmaxf(lmax, z[n * 64 + f]);
        atomicMax(&gmax[b0 * 64 + f], fmap(lmax));
    } else {
        int curb = b0; float lmax = -INFINITY;
        for (int n = base; n < end; ++n) {
            int b = batch[n];
            if (b != curb) {
                atomicMax(&gmax[curb * 64 + f], fmap(lmax));
                curb = b; lmax = -INFINITY;
            }
            lmax = fmaxf(lmax, z[n * 64 + f]);
        }
        atomicMax(&gmax[curb * 64 + f], fmap(lmax));
    }
}

__global__ void k_head(const unsigned* __restrict__ gmax,
                       const float* __restrict__ Wf1, const float* __restrict__ bf1,
                       const float* __restrict__ Wf2, const float* __restrict__ bf2,
                       const float* __restrict__ Wc, const float* __restrict__ bc,
                       const float* __restrict__ Wcb, const float* __restrict__ bcb,
                       float* __restrict__ out) {
    __shared__ float g[8][64], h1[8][32], h2[8][16];
    int t = threadIdx.x;  // 64 threads
    for (int i = t; i < 512; i += 64) g[i >> 6][i & 63] = funmap(gmax[i]);
    __syncthreads();
    for (int i = t; i < 256; i += 64) {
        int r = i >> 5, c = i & 31;
        float a = bf1[c];
        for (int k = 0; k < 64; ++k) a += g[r][k] * Wf1[k * 32 + c];
        h1[r][c] = fmaxf(a, 0.f);
    }
    __syncthreads();
    for (int i = t; i < 128; i += 64) {
        int r = i >> 4, c = i & 15;
        float a = bf2[c];
        for (int k = 0; k < 32; ++k) a += h1[r][k] * Wf2[k * 16 + c];
        h2[r][c] = fmaxf(a, 0.f);
    }
    __syncthreads();
    if (t < 16) {
        int r = t & 7;
        bool comb = t >= 8;
        const float* W = comb ? Wcb : Wc;
        float a = comb ? bcb[0] : bc[0];
        for (int k = 0; k < 16; ++k) a += h2[r][k] * W[k];
        out[(comb ? 8 : 0) + r] = a;
    }
}

// ---------- launch ----------
extern "C" void kernel_launch(void* const* d_in, const int* in_sizes, int n_in,
                              void* d_out, int out_size, void* d_ws, size_t ws_size,
                              hipStream_t stream) {
    const float* x    = (const float*)d_in[0];
    const int*   ei   = (const int*)d_in[1];
    const int*   batch= (const int*)d_in[2];
    const float* W1   = (const float*)d_in[3];
    const float* b1   = (const float*)d_in[4];
    const float* W2   = (const float*)d_in[5];
    const float* b2   = (const float*)d_in[6];
    const float* Wg1  = (const float*)d_in[7];
    const float* bg1  = (const float*)d_in[8];
    const float* Wg2  = (const float*)d_in[9];
    const float* bg2  = (const float*)d_in[10];
    const float* Wg3  = (const float*)d_in[11];
    const float* bg3  = (const float*)d_in[12];
    const float* Wsg  = (const float*)d_in[13];
    const float* bsg  = (const float*)d_in[14];
    const float* Wf1  = (const float*)d_in[15];
    const float* bf1  = (const float*)d_in[16];
    const float* Wf2  = (const float*)d_in[17];
    const float* bf2  = (const float*)d_in[18];
    const float* Wc   = (const float*)d_in[19];
    const float* bc   = (const float*)d_in[20];
    const float* Wcb  = (const float*)d_in[21];
    const float* bcb  = (const float*)d_in[22];

    const int N = in_sizes[0] / 16;
    const int E = in_sizes[1] / 2;
    const int* esrc = ei;
    const int* edst = ei + E;

    char* ws = (char*)d_ws;
    auto alloc = [&](size_t bytes) -> char* {
        char* p = ws;
        ws += (bytes + 255) & ~(size_t)255;
        return p;
    };
    int*      deg   = (int*)alloc((size_t)N * 4);
    int*      cnt   = (int*)alloc((size_t)N * 4);
    int*      rowst = (int*)alloc((size_t)(N + 1) * 4);
    int*      bsum  = (int*)alloc(4096);
    float*    dis   = (float*)alloc((size_t)N * 4);
    int*      col   = (int*)alloc((size_t)E * 4);
    float*    wgt   = (float*)alloc((size_t)E * 4);
    float*    bufA  = (float*)alloc((size_t)N * 64 * 4);
    float*    bufB  = (float*)alloc((size_t)N * 64 * 4);
    unsigned* gmax  = (unsigned*)alloc((size_t)G_GRAPHS * 64 * 4);

    hipMemsetAsync(deg, 0, (size_t)N * 4, stream);
    hipMemsetAsync(cnt, 0, (size_t)N * 4, stream);

    const int EB = (E + 255) / 256;
    const int NB = (N + 255) / 256;
    const int NW = (N + 3) / 4;   // wave-per-node grids

    k_count<<<EB, 256, 0, stream>>>(edst, deg, E);
    k_dis<<<NB, 256, 0, stream>>>(deg, dis, N);
    k_scanA<<<NB, 256, 0, stream>>>(deg, rowst, bsum, N);
    k_scanB<<<1, 512, 0, stream>>>(bsum, NB);
    k_scanC<<<NB, 256, 0, stream>>>(rowst, bsum, N);
    k_fill<<<EB, 256, 0, stream>>>(esrc, edst, dis, rowst, cnt, col, wgt, E);

    // encoder: y2 = relu(prop(x)@W1+b1)@W2
    k_enc<<<NW, 256, 0, stream>>>(x, bufA, dis, rowst, deg, col, wgt, W1, b1, W2, N);
    // z2 = prop(y2)+b2; out = z2@Wg1
    k_prop64<<<NW, 256, 0, stream>>>(bufA, bufB, dis, rowst, deg, col, wgt, b2, 0, Wg1, nullptr, N);
    // z3 = relu(prop(.)+bg1); out = z3@Wg2
    k_prop64<<<NW, 256, 0, stream>>>(bufB, bufA, dis, rowst, deg, col, wgt, bg1, 1, Wg2, nullptr, N);
    // z4 = relu(prop(.)+bg2); out = z4@Wg3
    k_prop64<<<NW, 256, 0, stream>>>(bufA, bufB, dis, rowst, deg, col, wgt, bg2, 1, Wg3, nullptr, N);
    // z5 = relu(prop(.)+bg3)
    k_prop64<<<NW, 256, 0, stream>>>(bufB, bufA, dis, rowst, deg, col, wgt, bg3, 1, nullptr, nullptr, N);
    // SGConv: 3 plain props, then prop + @Wsg + bsg
    k_prop64<<<NW, 256, 0, stream>>>(bufA, bufB, dis, rowst, deg, col, wgt, nullptr, 0, nullptr, nullptr, N);
    k_prop64<<<NW, 256, 0, stream>>>(bufB, bufA, dis, rowst, deg, col, wgt, nullptr, 0, nullptr, nullptr, N);
    k_prop64<<<NW, 256, 0, stream>>>(bufA, bufB, dis, rowst, deg, col, wgt, nullptr, 0, nullptr, nullptr, N);
    k_prop64<<<NW, 256, 0, stream>>>(bufB, bufA, dis, rowst, deg, col, wgt, nullptr, 0, Wsg, bsg, N);

    // pool + head
    k_pool_init<<<G_GRAPHS, 64, 0, stream>>>(gmax);
    k_pool<<<(N + 127) / 128, 256, 0, stream>>>(bufA, batch, gmax, N);
    k_head<<<1, 64, 0, stream>>>(gmax, Wf1, bf1, Wf2, bf2, Wc, bc, Wcb, bcb, (float*)d_out);
}

// Round 4
// 808.662 us; speedup vs baseline: 3.9779x; 3.9779x over previous
//
#include <hip/hip_runtime.h>
#include <hip/hip_bf16.h>
#include <math.h>

#define G_GRAPHS 8

// ---------- helpers ----------
__device__ __forceinline__ unsigned fmap(float f) {
    unsigned b = __float_as_uint(f);
    return (b & 0x80000000u) ? ~b : (b | 0x80000000u);
}
__device__ __forceinline__ float funmap(unsigned u) {
    unsigned b = (u & 0x80000000u) ? (u & 0x7fffffffu) : ~u;
    return __uint_as_float(b);
}

// ---------- CSR build ----------
__global__ void k_count(const int* __restrict__ dst, int* __restrict__ deg, int E) {
    int e = blockIdx.x * 256 + threadIdx.x;
    if (e < E) atomicAdd(&deg[dst[e]], 1);
}

__global__ void k_dis(const int* __restrict__ deg, float* __restrict__ dis, int N) {
    int i = blockIdx.x * 256 + threadIdx.x;
    if (i < N) dis[i] = rsqrtf((float)(deg[i] + 1));  // +1 = self loop
}

__global__ void k_scanA(const int* __restrict__ deg, int* __restrict__ rowst,
                        int* __restrict__ bsum, int N) {
    __shared__ int s[256];
    int i = blockIdx.x * 256 + threadIdx.x;
    int v = (i < N) ? deg[i] : 0;
    s[threadIdx.x] = v;
    __syncthreads();
    for (int off = 1; off < 256; off <<= 1) {
        int t = (threadIdx.x >= off) ? s[threadIdx.x - off] : 0;
        __syncthreads();
        s[threadIdx.x] += t;
        __syncthreads();
    }
    if (i < N) rowst[i] = s[threadIdx.x] - v;   // block-local exclusive
    if (threadIdx.x == 255) bsum[blockIdx.x] = s[255];
}

__global__ void k_scanB(int* __restrict__ bsum, int NB) {
    __shared__ int s[512];
    int t = threadIdx.x;
    int v = (t < NB) ? bsum[t] : 0;
    s[t] = v;
    __syncthreads();
    for (int off = 1; off < 512; off <<= 1) {
        int x = (t >= off) ? s[t - off] : 0;
        __syncthreads();
        s[t] += x;
        __syncthreads();
    }
    if (t < NB) bsum[t] = s[t] - v;             // exclusive
}

__global__ void k_scanC(int* __restrict__ rowst, const int* __restrict__ bsum, int N) {
    int i = blockIdx.x * 256 + threadIdx.x;
    if (i < N) rowst[i] += bsum[blockIdx.x];
}

__global__ void k_fill(const int* __restrict__ src, const int* __restrict__ dst,
                       const float* __restrict__ dis, const int* __restrict__ rowst,
                       int* __restrict__ cnt, int2* __restrict__ edge, int E) {
    int e = blockIdx.x * 256 + threadIdx.x;
    if (e >= E) return;
    int d = dst[e], s = src[e];
    int p = rowst[d] + atomicAdd(&cnt[d], 1);
    edge[p] = make_int2(s, __float_as_int(dis[s] * dis[d]));
}

// ---------- encoder: out = relu(prop(x)@W1+b1)@W2  (wave per node) ----------
__global__ __launch_bounds__(256) void k_enc(
        const float* __restrict__ x, float* __restrict__ out,
        const float* __restrict__ dis, const int* __restrict__ rowst,
        const int* __restrict__ deg, const int2* __restrict__ edge,
        const float* __restrict__ W1, const float* __restrict__ b1,
        const float* __restrict__ W2, int N) {
    __shared__ float prow[4][16];
    __shared__ float z1buf[4][128];
    int t = threadIdx.x, lane = t & 63, w = t >> 6;
    int qq = lane & 3, e = lane >> 2;          // 16 edge groups x 4 lanes (float4)
    int node = blockIdx.x * 4 + w;
    if (node >= N) return;
    const float4* x4 = (const float4*)x;
    float d = dis[node];
    float sc = d * d * (1.f / 16.f);           // self-loop spread over 16 groups
    float4 sf = x4[node * 4 + qq];
    float ax = sf.x * sc, ay = sf.y * sc, az = sf.z * sc, aw = sf.w * sc;
    int s = rowst[node], dg = deg[node];
    const int2* ep = edge + s;
    int i = e;
    for (; i + 16 < dg; i += 32) {             // unroll x2: edges i, i+16
        int2 e0 = ep[i], e1 = ep[i + 16];
        float4 r0 = x4[e0.x * 4 + qq];
        float4 r1 = x4[e1.x * 4 + qq];
        float w0 = __int_as_float(e0.y), w1 = __int_as_float(e1.y);
        ax += w0 * r0.x; ay += w0 * r0.y; az += w0 * r0.z; aw += w0 * r0.w;
        ax += w1 * r1.x; ay += w1 * r1.y; az += w1 * r1.z; aw += w1 * r1.w;
    }
    if (i < dg) {
        int2 e0 = ep[i];
        float4 r0 = x4[e0.x * 4 + qq];
        float w0 = __int_as_float(e0.y);
        ax += w0 * r0.x; ay += w0 * r0.y; az += w0 * r0.z; aw += w0 * r0.w;
    }
    ax += __shfl_xor(ax, 4);  ay += __shfl_xor(ay, 4);  az += __shfl_xor(az, 4);  aw += __shfl_xor(aw, 4);
    ax += __shfl_xor(ax, 8);  ay += __shfl_xor(ay, 8);  az += __shfl_xor(az, 8);  aw += __shfl_xor(aw, 8);
    ax += __shfl_xor(ax, 16); ay += __shfl_xor(ay, 16); az += __shfl_xor(az, 16); aw += __shfl_xor(aw, 16);
    ax += __shfl_xor(ax, 32); ay += __shfl_xor(ay, 32); az += __shfl_xor(az, 32); aw += __shfl_xor(aw, 32);
    if (lane < 4)
        ((float4*)prow[w])[lane] = make_float4(ax, ay, az, aw);
    // z1 = relu(p@W1+b1): each lane produces features lane, lane+64
    float a0 = b1[lane], a1 = b1[lane + 64];
    for (int k = 0; k < 16; ++k) {
        float p = prow[w][k];
        a0 += p * W1[k * 128 + lane];
        a1 += p * W1[k * 128 + lane + 64];
    }
    z1buf[w][lane] = fmaxf(a0, 0.f);
    z1buf[w][lane + 64] = fmaxf(a1, 0.f);
    // y2 = z1@W2
    float a = 0.f;
    for (int k = 0; k < 128; ++k)
        a += z1buf[w][k] * W2[k * 64 + lane];
    out[node * 64 + lane] = a;
}

// ---------- prop64: z = prop(in)+bias [relu]; out = W ? z@W (+gbias) : z ----------
__global__ __launch_bounds__(256) void k_prop64(
        const float* __restrict__ in, float* __restrict__ out,
        const float* __restrict__ dis, const int* __restrict__ rowst,
        const int* __restrict__ deg, const int2* __restrict__ edge,
        const float* __restrict__ bias, int relu,
        const float* __restrict__ W, const float* __restrict__ gbias, int N) {
    __shared__ float rowbuf[4][64];
    int t = threadIdx.x, lane = t & 63, w = t >> 6;
    int q = lane & 15, g = lane >> 4;          // 4 edge groups x 16 lanes (float4)
    int node = blockIdx.x * 4 + w;
    if (node >= N) return;
    const float4* in4 = (const float4*)in;
    float d = dis[node];
    float sc = d * d * 0.25f;                  // self-loop spread over 4 groups
    float4 sf = in4[node * 16 + q];
    float ax = sf.x * sc, ay = sf.y * sc, az = sf.z * sc, aw = sf.w * sc;
    int s = rowst[node], dg = deg[node];
    const int2* ep = edge + s;
    int i = g;
    for (; i + 4 < dg; i += 8) {               // unroll x2: edges i, i+4
        int2 e0 = ep[i], e1 = ep[i + 4];
        float4 r0 = in4[e0.x * 16 + q];
        float4 r1 = in4[e1.x * 16 + q];
        float w0 = __int_as_float(e0.y), w1 = __int_as_float(e1.y);
        ax += w0 * r0.x; ay += w0 * r0.y; az += w0 * r0.z; aw += w0 * r0.w;
        ax += w1 * r1.x; ay += w1 * r1.y; az += w1 * r1.z; aw += w1 * r1.w;
    }
    if (i < dg) {
        int2 e0 = ep[i];
        float4 r0 = in4[e0.x * 16 + q];
        float w0 = __int_as_float(e0.y);
        ax += w0 * r0.x; ay += w0 * r0.y; az += w0 * r0.z; aw += w0 * r0.w;
    }
    // reduce 4 edge-groups: xor 16, 32
    ax += __shfl_xor(ax, 16); ay += __shfl_xor(ay, 16); az += __shfl_xor(az, 16); aw += __shfl_xor(aw, 16);
    ax += __shfl_xor(ax, 32); ay += __shfl_xor(ay, 32); az += __shfl_xor(az, 32); aw += __shfl_xor(aw, 32);
    if (bias) {
        float4 b4 = ((const float4*)bias)[q];
        ax += b4.x; ay += b4.y; az += b4.z; aw += b4.w;
    }
    if (relu) {
        ax = fmaxf(ax, 0.f); ay = fmaxf(ay, 0.f); az = fmaxf(az, 0.f); aw = fmaxf(aw, 0.f);
    }
    if (!W) {
        if (g == 0)
            ((float4*)out)[node * 16 + q] = make_float4(ax, ay, az, aw);
    } else {
        if (g == 0)
            ((float4*)rowbuf[w])[q] = make_float4(ax, ay, az, aw);
        float a = gbias ? gbias[lane] : 0.f;
        for (int k = 0; k < 64; ++k)
            a += rowbuf[w][k] * W[k * 64 + lane];
        out[node * 64 + lane] = a;
    }
}

// ---------- pooling + head ----------
__global__ void k_pool_init(unsigned* __restrict__ gmax) {
    gmax[blockIdx.x * 64 + threadIdx.x] = fmap(-INFINITY);
}

__global__ void k_pool(const float* __restrict__ z, const int* __restrict__ batch,
                       unsigned* __restrict__ gmax, int N) {
    int f = threadIdx.x & 63, w = threadIdx.x >> 6;
    int base = (blockIdx.x * 4 + w) * 32;
    if (base >= N) return;
    int end = base + 32; if (end > N) end = N;
    int b0 = batch[base], b1 = batch[end - 1];
    if (b0 == b1) {                            // fast path: single graph in window
        float lmax = -INFINITY;
        for (int n = base; n < end; ++n)
            lmax = fmaxf(lmax, z[n * 64 + f]);
        atomicMax(&gmax[b0 * 64 + f], fmap(lmax));
    } else {
        int curb = b0; float lmax = -INFINITY;
        for (int n = base; n < end; ++n) {
            int b = batch[n];
            if (b != curb) {
                atomicMax(&gmax[curb * 64 + f], fmap(lmax));
                curb = b; lmax = -INFINITY;
            }
            lmax = fmaxf(lmax, z[n * 64 + f]);
        }
        atomicMax(&gmax[curb * 64 + f], fmap(lmax));
    }
}

__global__ void k_head(const unsigned* __restrict__ gmax,
                       const float* __restrict__ Wf1, const float* __restrict__ bf1,
                       const float* __restrict__ Wf2, const float* __restrict__ bf2,
                       const float* __restrict__ Wc, const float* __restrict__ bc,
                       const float* __restrict__ Wcb, const float* __restrict__ bcb,
                       float* __restrict__ out) {
    __shared__ float g[8][64], h1[8][32], h2[8][16];
    int t = threadIdx.x;  // 64 threads
    for (int i = t; i < 512; i += 64) g[i >> 6][i & 63] = funmap(gmax[i]);
    __syncthreads();
    for (int i = t; i < 256; i += 64) {
        int r = i >> 5, c = i & 31;
        float a = bf1[c];
        for (int k = 0; k < 64; ++k) a += g[r][k] * Wf1[k * 32 + c];
        h1[r][c] = fmaxf(a, 0.f);
    }
    __syncthreads();
    for (int i = t; i < 128; i += 64) {
        int r = i >> 4, c = i & 15;
        float a = bf2[c];
        for (int k = 0; k < 32; ++k) a += h1[r][k] * Wf2[k * 16 + c];
        h2[r][c] = fmaxf(a, 0.f);
    }
    __syncthreads();
    if (t < 16) {
        int r = t & 7;
        bool comb = t >= 8;
        const float* W = comb ? Wcb : Wc;
        float a = comb ? bcb[0] : bc[0];
        for (int k = 0; k < 16; ++k) a += h2[r][k] * W[k];
        out[(comb ? 8 : 0) + r] = a;
    }
}

// ---------- launch ----------
extern "C" void kernel_launch(void* const* d_in, const int* in_sizes, int n_in,
                              void* d_out, int out_size, void* d_ws, size_t ws_size,
                              hipStream_t stream) {
    const float* x    = (const float*)d_in[0];
    const int*   ei   = (const int*)d_in[1];
    const int*   batch= (const int*)d_in[2];
    const float* W1   = (const float*)d_in[3];
    const float* b1   = (const float*)d_in[4];
    const float* W2   = (const float*)d_in[5];
    const float* b2   = (const float*)d_in[6];
    const float* Wg1  = (const float*)d_in[7];
    const float* bg1  = (const float*)d_in[8];
    const float* Wg2  = (const float*)d_in[9];
    const float* bg2  = (const float*)d_in[10];
    const float* Wg3  = (const float*)d_in[11];
    const float* bg3  = (const float*)d_in[12];
    const float* Wsg  = (const float*)d_in[13];
    const float* bsg  = (const float*)d_in[14];
    const float* Wf1  = (const float*)d_in[15];
    const float* bf1  = (const float*)d_in[16];
    const float* Wf2  = (const float*)d_in[17];
    const float* bf2  = (const float*)d_in[18];
    const float* Wc   = (const float*)d_in[19];
    const float* bc   = (const float*)d_in[20];
    const float* Wcb  = (const float*)d_in[21];
    const float* bcb  = (const float*)d_in[22];

    const int N = in_sizes[0] / 16;
    const int E = in_sizes[1] / 2;
    const int* esrc = ei;
    const int* edst = ei + E;

    char* ws = (char*)d_ws;
    auto alloc = [&](size_t bytes) -> char* {
        char* p = ws;
        ws += (bytes + 255) & ~(size_t)255;
        return p;
    };
    int*      deg   = (int*)alloc((size_t)N * 4);
    int*      cnt   = (int*)alloc((size_t)N * 4);
    int*      rowst = (int*)alloc((size_t)(N + 1) * 4);
    int*      bsum  = (int*)alloc(4096);
    float*    dis   = (float*)alloc((size_t)N * 4);
    int2*     edge  = (int2*)alloc((size_t)E * 8);
    float*    bufA  = (float*)alloc((size_t)N * 64 * 4);
    float*    bufB  = (float*)alloc((size_t)N * 64 * 4);
    unsigned* gmax  = (unsigned*)alloc((size_t)G_GRAPHS * 64 * 4);

    hipMemsetAsync(deg, 0, (size_t)N * 4, stream);
    hipMemsetAsync(cnt, 0, (size_t)N * 4, stream);

    const int EB = (E + 255) / 256;
    const int NB = (N + 255) / 256;
    const int NW = (N + 3) / 4;   // wave-per-node grids

    k_count<<<EB, 256, 0, stream>>>(edst, deg, E);
    k_dis<<<NB, 256, 0, stream>>>(deg, dis, N);
    k_scanA<<<NB, 256, 0, stream>>>(deg, rowst, bsum, N);
    k_scanB<<<1, 512, 0, stream>>>(bsum, NB);
    k_scanC<<<NB, 256, 0, stream>>>(rowst, bsum, N);
    k_fill<<<EB, 256, 0, stream>>>(esrc, edst, dis, rowst, cnt, edge, E);

    // encoder: y2 = relu(prop(x)@W1+b1)@W2
    k_enc<<<NW, 256, 0, stream>>>(x, bufA, dis, rowst, deg, edge, W1, b1, W2, N);
    // z2 = prop(y2)+b2; out = z2@Wg1
    k_prop64<<<NW, 256, 0, stream>>>(bufA, bufB, dis, rowst, deg, edge, b2, 0, Wg1, nullptr, N);
    // z3 = relu(prop(.)+bg1); out = z3@Wg2
    k_prop64<<<NW, 256, 0, stream>>>(bufB, bufA, dis, rowst, deg, edge, bg1, 1, Wg2, nullptr, N);
    // z4 = relu(prop(.)+bg2); out = z4@Wg3
    k_prop64<<<NW, 256, 0, stream>>>(bufA, bufB, dis, rowst, deg, edge, bg2, 1, Wg3, nullptr, N);
    // z5 = relu(prop(.)+bg3)
    k_prop64<<<NW, 256, 0, stream>>>(bufB, bufA, dis, rowst, deg, edge, bg3, 1, nullptr, nullptr, N);
    // SGConv: 3 plain props, then prop + @Wsg + bsg
    k_prop64<<<NW, 256, 0, stream>>>(bufA, bufB, dis, rowst, deg, edge, nullptr, 0, nullptr, nullptr, N);
    k_prop64<<<NW, 256, 0, stream>>>(bufB, bufA, dis, rowst, deg, edge, nullptr, 0, nullptr, nullptr, N);
    k_prop64<<<NW, 256, 0, stream>>>(bufA, bufB, dis, rowst, deg, edge, nullptr, 0, nullptr, nullptr, N);
    k_prop64<<<NW, 256, 0, stream>>>(bufB, bufA, dis, rowst, deg, edge, nullptr, 0, Wsg, bsg, N);

    // pool + head
    k_pool_init<<<G_GRAPHS, 64, 0, stream>>>(gmax);
    k_pool<<<(N + 127) / 128, 256, 0, stream>>>(bufA, batch, gmax, N);
    k_head<<<1, 64, 0, stream>>>(gmax, Wf1, bf1, Wf2, bf2, Wc, bc, Wcb, bcb, (float*)d_out);
}

// Round 5
// 773.668 us; speedup vs baseline: 4.1578x; 1.0452x over previous
//
#include <hip/hip_runtime.h>
#include <hip/hip_bf16.h>
#include <math.h>

#define G_GRAPHS 8

// ---------- helpers ----------
__device__ __forceinline__ unsigned fmap(float f) {
    unsigned b = __float_as_uint(f);
    return (b & 0x80000000u) ? ~b : (b | 0x80000000u);
}
__device__ __forceinline__ float funmap(unsigned u) {
    unsigned b = (u & 0x80000000u) ? (u & 0x7fffffffu) : ~u;
    return __uint_as_float(b);
}

// ---------- CSR build ----------
__global__ void k_count(const int* __restrict__ dst, int* __restrict__ deg, int E) {
    int e = blockIdx.x * 256 + threadIdx.x;
    if (e < E) atomicAdd(&deg[dst[e]], 1);
}

__global__ void k_dis(const int* __restrict__ deg, float* __restrict__ dis, int N) {
    int i = blockIdx.x * 256 + threadIdx.x;
    if (i < N) dis[i] = rsqrtf((float)(deg[i] + 1));  // +1 = self loop
}

__global__ void k_scanA(const int* __restrict__ deg, int* __restrict__ rowst,
                        int* __restrict__ bsum, int N) {
    __shared__ int s[256];
    int i = blockIdx.x * 256 + threadIdx.x;
    int v = (i < N) ? deg[i] : 0;
    s[threadIdx.x] = v;
    __syncthreads();
    for (int off = 1; off < 256; off <<= 1) {
        int t = (threadIdx.x >= off) ? s[threadIdx.x - off] : 0;
        __syncthreads();
        s[threadIdx.x] += t;
        __syncthreads();
    }
    if (i < N) rowst[i] = s[threadIdx.x] - v;   // block-local exclusive
    if (threadIdx.x == 255) bsum[blockIdx.x] = s[255];
}

__global__ void k_scanB(int* __restrict__ bsum, int NB) {
    __shared__ int s[512];
    int t = threadIdx.x;
    int v = (t < NB) ? bsum[t] : 0;
    s[t] = v;
    __syncthreads();
    for (int off = 1; off < 512; off <<= 1) {
        int x = (t >= off) ? s[t - off] : 0;
        __syncthreads();
        s[t] += x;
        __syncthreads();
    }
    if (t < NB) bsum[t] = s[t] - v;             // exclusive
}

__global__ void k_scanC(int* __restrict__ rowst, const int* __restrict__ bsum, int N) {
    int i = blockIdx.x * 256 + threadIdx.x;
    if (i < N) rowst[i] += bsum[blockIdx.x];
}

__global__ void k_fill(const int* __restrict__ src, const int* __restrict__ dst,
                       const float* __restrict__ dis, const int* __restrict__ rowst,
                       int* __restrict__ cnt, int2* __restrict__ edge, int E) {
    int e = blockIdx.x * 256 + threadIdx.x;
    if (e >= E) return;
    int d = dst[e], s = src[e];
    int p = rowst[d] + atomicAdd(&cnt[d], 1);
    edge[p] = make_int2(s, __float_as_int(dis[s] * dis[d]));
}

// ---------- encoder (persistent): out = relu(prop(x)@W1+b1)@W2 ----------
__global__ __launch_bounds__(256) void k_enc(
        const float* __restrict__ x, float* __restrict__ out,
        const float* __restrict__ dis, const int* __restrict__ rowst,
        const int* __restrict__ deg, const int2* __restrict__ edge,
        const float* __restrict__ W1, const float* __restrict__ b1,
        const float* __restrict__ W2, int N) {
    __shared__ float W1l[16 * 128];
    __shared__ float W2l[128 * 64];
    __shared__ float prow[4][16];
    __shared__ float4 z1T[128];   // z1T[k] = {node0..3}[feature k]
    int t = threadIdx.x, lane = t & 63, w = t >> 6;
    int qq = lane & 3, e = lane >> 2;          // 16 edge groups x 4 lanes (float4)
    // stage weights once per block
    for (int i = t; i < 16 * 128 / 4; i += 256) ((float4*)W1l)[i] = ((const float4*)W1)[i];
    for (int i = t; i < 128 * 64 / 4; i += 256) ((float4*)W2l)[i] = ((const float4*)W2)[i];
    __syncthreads();
    float b1a = b1[lane], b1b = b1[lane + 64];
    const float4* x4 = (const float4*)x;
    int nquad = (N + 3) >> 2;
    for (int qi = blockIdx.x; qi < nquad; qi += gridDim.x) {
        int node = qi * 4 + w;
        bool valid = node < N;
        float ax = 0.f, ay = 0.f, az = 0.f, aw = 0.f;
        if (valid) {
            float d = dis[node];
            float sc = d * d * (1.f / 16.f);
            float4 sf = x4[node * 4 + qq];
            ax = sf.x * sc; ay = sf.y * sc; az = sf.z * sc; aw = sf.w * sc;
            int s = rowst[node], dg = deg[node];
            const int2* ep = edge + s;
            int i = e;
            for (; i + 16 < dg; i += 32) {
                int2 e0 = ep[i], e1 = ep[i + 16];
                float4 r0 = x4[e0.x * 4 + qq];
                float4 r1 = x4[e1.x * 4 + qq];
                float w0 = __int_as_float(e0.y), w1 = __int_as_float(e1.y);
                ax += w0 * r0.x; ay += w0 * r0.y; az += w0 * r0.z; aw += w0 * r0.w;
                ax += w1 * r1.x; ay += w1 * r1.y; az += w1 * r1.z; aw += w1 * r1.w;
            }
            if (i < dg) {
                int2 e0 = ep[i];
                float4 r0 = x4[e0.x * 4 + qq];
                float w0 = __int_as_float(e0.y);
                ax += w0 * r0.x; ay += w0 * r0.y; az += w0 * r0.z; aw += w0 * r0.w;
            }
        }
        ax += __shfl_xor(ax, 4);  ay += __shfl_xor(ay, 4);  az += __shfl_xor(az, 4);  aw += __shfl_xor(aw, 4);
        ax += __shfl_xor(ax, 8);  ay += __shfl_xor(ay, 8);  az += __shfl_xor(az, 8);  aw += __shfl_xor(aw, 8);
        ax += __shfl_xor(ax, 16); ay += __shfl_xor(ay, 16); az += __shfl_xor(az, 16); aw += __shfl_xor(aw, 16);
        ax += __shfl_xor(ax, 32); ay += __shfl_xor(ay, 32); az += __shfl_xor(az, 32); aw += __shfl_xor(aw, 32);
        if (lane < 4)
            ((float4*)prow[w])[lane] = make_float4(ax, ay, az, aw);  // wave-local
        float z0 = 0.f, z1 = 0.f;
        if (valid) {
            z0 = b1a; z1 = b1b;
            for (int k = 0; k < 16; ++k) {
                float p = prow[w][k];
                z0 += p * W1l[k * 128 + lane];
                z1 += p * W1l[k * 128 + lane + 64];
            }
            z0 = fmaxf(z0, 0.f); z1 = fmaxf(z1, 0.f);
        }
        ((float*)&z1T[lane])[w]      = z0;
        ((float*)&z1T[lane + 64])[w] = z1;
        __syncthreads();
        if (w == 0) {   // one wave: y2 = z1@W2 for the 4 nodes
            int base = qi * 4;
            float a0 = 0.f, a1 = 0.f, a2 = 0.f, a3 = 0.f;
            for (int k = 0; k < 128; ++k) {
                float wk = W2l[k * 64 + lane];
                float4 z = z1T[k];
                a0 += z.x * wk; a1 += z.y * wk; a2 += z.z * wk; a3 += z.w * wk;
            }
            if (base + 0 < N) out[(base + 0) * 64 + lane] = a0;
            if (base + 1 < N) out[(base + 1) * 64 + lane] = a1;
            if (base + 2 < N) out[(base + 2) * 64 + lane] = a2;
            if (base + 3 < N) out[(base + 3) * 64 + lane] = a3;
        }
        __syncthreads();
    }
}

// ---------- prop64 (persistent, 2 nodes/wave): z = prop(in)+bias [relu]; out = W ? z@W(+gbias) : z
__global__ __launch_bounds__(256) void k_prop64(
        const float* __restrict__ in, float* __restrict__ out,
        const float* __restrict__ dis, const int* __restrict__ rowst,
        const int* __restrict__ deg, const int2* __restrict__ edge,
        const float* __restrict__ bias, int relu,
        const float* __restrict__ W, const float* __restrict__ gbias, int N) {
    __shared__ float Wlds[64 * 64];
    __shared__ float zbuf[4][2][64];
    int t = threadIdx.x, lane = t & 63, w = t >> 6;
    int q = lane & 15, g = lane >> 4;          // 4 edge groups x 16 lanes (float4)
    const float4* in4 = (const float4*)in;
    if (W) {
        for (int i = t; i < 64 * 64 / 4; i += 256)
            ((float4*)Wlds)[i] = ((const float4*)W)[i];
        __syncthreads();
    }
    float4 b4 = make_float4(0.f, 0.f, 0.f, 0.f);
    if (bias) b4 = ((const float4*)bias)[q];
    float gb = (W && gbias) ? gbias[lane] : 0.f;
    int wid = blockIdx.x * 4 + w;
    const int stride = gridDim.x * 4 * 2;
    for (int n0 = wid * 2; n0 < N; n0 += stride) {
        int n1 = n0 + 1;
        bool h1 = n1 < N;
        int s0 = rowst[n0], d0 = deg[n0];
        int s1 = h1 ? rowst[n1] : s0, d1 = h1 ? deg[n1] : 0;
        float di0 = dis[n0];
        float di1 = h1 ? dis[n1] : 0.f;
        const int2* e0 = edge + s0;
        const int2* e1 = edge + s1;
        float4 sf0 = in4[n0 * 16 + q];
        float4 sf1 = h1 ? in4[n1 * 16 + q] : sf0;
        float sc0 = di0 * di0 * 0.25f, sc1 = di1 * di1 * 0.25f;
        float a0x = sf0.x*sc0, a0y = sf0.y*sc0, a0z = sf0.z*sc0, a0w = sf0.w*sc0;
        float a1x = sf1.x*sc1, a1y = sf1.y*sc1, a1z = sf1.z*sc1, a1w = sf1.w*sc1;
        int m = d0 > d1 ? d0 : d1;
        for (int base = 0; base < m; base += 8) {
            int i = base + g, j = base + g + 4;
            int2 m0a = e0[(i < d0) ? i : 0];
            int2 m0b = e0[(j < d0) ? j : 0];
            int2 m1a = e1[(i < d1) ? i : 0];
            int2 m1b = e1[(j < d1) ? j : 0];
            float4 r0a = in4[m0a.x * 16 + q];
            float4 r0b = in4[m0b.x * 16 + q];
            float4 r1a = in4[m1a.x * 16 + q];
            float4 r1b = in4[m1b.x * 16 + q];
            float w0a = (i < d0) ? __int_as_float(m0a.y) : 0.f;
            float w0b = (j < d0) ? __int_as_float(m0b.y) : 0.f;
            float w1a = (i < d1) ? __int_as_float(m1a.y) : 0.f;
            float w1b = (j < d1) ? __int_as_float(m1b.y) : 0.f;
            a0x += w0a*r0a.x; a0y += w0a*r0a.y; a0z += w0a*r0a.z; a0w += w0a*r0a.w;
            a0x += w0b*r0b.x; a0y += w0b*r0b.y; a0z += w0b*r0b.z; a0w += w0b*r0b.w;
            a1x += w1a*r1a.x; a1y += w1a*r1a.y; a1z += w1a*r1a.z; a1w += w1a*r1a.w;
            a1x += w1b*r1b.x; a1y += w1b*r1b.y; a1z += w1b*r1b.z; a1w += w1b*r1b.w;
        }
        // reduce the 4 edge-groups: xor 16, 32
        a0x += __shfl_xor(a0x,16); a0y += __shfl_xor(a0y,16); a0z += __shfl_xor(a0z,16); a0w += __shfl_xor(a0w,16);
        a0x += __shfl_xor(a0x,32); a0y += __shfl_xor(a0y,32); a0z += __shfl_xor(a0z,32); a0w += __shfl_xor(a0w,32);
        a1x += __shfl_xor(a1x,16); a1y += __shfl_xor(a1y,16); a1z += __shfl_xor(a1z,16); a1w += __shfl_xor(a1w,16);
        a1x += __shfl_xor(a1x,32); a1y += __shfl_xor(a1y,32); a1z += __shfl_xor(a1z,32); a1w += __shfl_xor(a1w,32);
        a0x += b4.x; a0y += b4.y; a0z += b4.z; a0w += b4.w;
        a1x += b4.x; a1y += b4.y; a1z += b4.z; a1w += b4.w;
        if (relu) {
            a0x = fmaxf(a0x,0.f); a0y = fmaxf(a0y,0.f); a0z = fmaxf(a0z,0.f); a0w = fmaxf(a0w,0.f);
            a1x = fmaxf(a1x,0.f); a1y = fmaxf(a1y,0.f); a1z = fmaxf(a1z,0.f); a1w = fmaxf(a1w,0.f);
        }
        if (!W) {
            if (g == 0) {
                ((float4*)out)[n0 * 16 + q] = make_float4(a0x, a0y, a0z, a0w);
                if (h1) ((float4*)out)[n1 * 16 + q] = make_float4(a1x, a1y, a1z, a1w);
            }
        } else {
            if (g == 0) {
                ((float4*)zbuf[w][0])[q] = make_float4(a0x, a0y, a0z, a0w);
                ((float4*)zbuf[w][1])[q] = make_float4(a1x, a1y, a1z, a1w);
            }
            // wave-local LDS RAW: in-order per wave, compiler inserts lgkmcnt wait
            float acc0 = gb, acc1 = gb;
            for (int k = 0; k < 64; ++k) {
                float wk = Wlds[k * 64 + lane];
                acc0 += zbuf[w][0][k] * wk;
                acc1 += zbuf[w][1][k] * wk;
            }
            out[n0 * 64 + lane] = acc0;
            if (h1) out[n1 * 64 + lane] = acc1;
        }
    }
}

// ---------- pooling + head ----------
__global__ void k_pool_init(unsigned* __restrict__ gmax) {
    gmax[blockIdx.x * 64 + threadIdx.x] = fmap(-INFINITY);
}

__global__ void k_pool(const float* __restrict__ z, const int* __restrict__ batch,
                       unsigned* __restrict__ gmax, int N) {
    int f = threadIdx.x & 63, w = threadIdx.x >> 6;
    int base = (blockIdx.x * 4 + w) * 32;
    if (base >= N) return;
    int end = base + 32; if (end > N) end = N;
    int b0 = batch[base], b1 = batch[end - 1];
    if (b0 == b1) {                            // fast path: single graph in window
        float lmax = -INFINITY;
        for (int n = base; n < end; ++n)
            lmax = fmaxf(lmax, z[n * 64 + f]);
        atomicMax(&gmax[b0 * 64 + f], fmap(lmax));
    } else {
        int curb = b0; float lmax = -INFINITY;
        for (int n = base; n < end; ++n) {
            int b = batch[n];
            if (b != curb) {
                atomicMax(&gmax[curb * 64 + f], fmap(lmax));
                curb = b; lmax = -INFINITY;
            }
            lmax = fmaxf(lmax, z[n * 64 + f]);
        }
        atomicMax(&gmax[curb * 64 + f], fmap(lmax));
    }
}

__global__ void k_head(const unsigned* __restrict__ gmax,
                       const float* __restrict__ Wf1, const float* __restrict__ bf1,
                       const float* __restrict__ Wf2, const float* __restrict__ bf2,
                       const float* __restrict__ Wc, const float* __restrict__ bc,
                       const float* __restrict__ Wcb, const float* __restrict__ bcb,
                       float* __restrict__ out) {
    __shared__ float g[8][64], h1[8][32], h2[8][16];
    int t = threadIdx.x;  // 64 threads
    for (int i = t; i < 512; i += 64) g[i >> 6][i & 63] = funmap(gmax[i]);
    __syncthreads();
    for (int i = t; i < 256; i += 64) {
        int r = i >> 5, c = i & 31;
        float a = bf1[c];
        for (int k = 0; k < 64; ++k) a += g[r][k] * Wf1[k * 32 + c];
        h1[r][c] = fmaxf(a, 0.f);
    }
    __syncthreads();
    for (int i = t; i < 128; i += 64) {
        int r = i >> 4, c = i & 15;
        float a = bf2[c];
        for (int k = 0; k < 32; ++k) a += h1[r][k] * Wf2[k * 16 + c];
        h2[r][c] = fmaxf(a, 0.f);
    }
    __syncthreads();
    if (t < 16) {
        int r = t & 7;
        bool comb = t >= 8;
        const float* W = comb ? Wcb : Wc;
        float a = comb ? bcb[0] : bc[0];
        for (int k = 0; k < 16; ++k) a += h2[r][k] * W[k];
        out[(comb ? 8 : 0) + r] = a;
    }
}

// ---------- launch ----------
extern "C" void kernel_launch(void* const* d_in, const int* in_sizes, int n_in,
                              void* d_out, int out_size, void* d_ws, size_t ws_size,
                              hipStream_t stream) {
    const float* x    = (const float*)d_in[0];
    const int*   ei   = (const int*)d_in[1];
    const int*   batch= (const int*)d_in[2];
    const float* W1   = (const float*)d_in[3];
    const float* b1   = (const float*)d_in[4];
    const float* W2   = (const float*)d_in[5];
    const float* b2   = (const float*)d_in[6];
    const float* Wg1  = (const float*)d_in[7];
    const float* bg1  = (const float*)d_in[8];
    const float* Wg2  = (const float*)d_in[9];
    const float* bg2  = (const float*)d_in[10];
    const float* Wg3  = (const float*)d_in[11];
    const float* bg3  = (const float*)d_in[12];
    const float* Wsg  = (const float*)d_in[13];
    const float* bsg  = (const float*)d_in[14];
    const float* Wf1  = (const float*)d_in[15];
    const float* bf1  = (const float*)d_in[16];
    const float* Wf2  = (const float*)d_in[17];
    const float* bf2  = (const float*)d_in[18];
    const float* Wc   = (const float*)d_in[19];
    const float* bc   = (const float*)d_in[20];
    const float* Wcb  = (const float*)d_in[21];
    const float* bcb  = (const float*)d_in[22];

    const int N = in_sizes[0] / 16;
    const int E = in_sizes[1] / 2;
    const int* esrc = ei;
    const int* edst = ei + E;

    char* ws = (char*)d_ws;
    auto alloc = [&](size_t bytes) -> char* {
        char* p = ws;
        ws += (bytes + 255) & ~(size_t)255;
        return p;
    };
    int*      deg   = (int*)alloc((size_t)N * 4);
    int*      cnt   = (int*)alloc((size_t)N * 4);
    int*      rowst = (int*)alloc((size_t)(N + 1) * 4);
    int*      bsum  = (int*)alloc(4096);
    float*    dis   = (float*)alloc((size_t)N * 4);
    int2*     edge  = (int2*)alloc((size_t)(E + 16) * 8);
    float*    bufA  = (float*)alloc((size_t)N * 64 * 4);
    float*    bufB  = (float*)alloc((size_t)N * 64 * 4);
    unsigned* gmax  = (unsigned*)alloc((size_t)G_GRAPHS * 64 * 4);

    hipMemsetAsync(deg, 0, (size_t)N * 4, stream);
    hipMemsetAsync(cnt, 0, (size_t)N * 4, stream);
    hipMemsetAsync(edge + E, 0, 16 * 8, stream);   // zero pad for clamped loads

    const int EB = (E + 255) / 256;
    const int NB = (N + 255) / 256;
    const int PB = 2048;   // persistent prop blocks (8/CU)
    const int CB = 768;    // persistent enc blocks (3/CU, 42KB LDS)

    k_count<<<EB, 256, 0, stream>>>(edst, deg, E);
    k_dis<<<NB, 256, 0, stream>>>(deg, dis, N);
    k_scanA<<<NB, 256, 0, stream>>>(deg, rowst, bsum, N);
    k_scanB<<<1, 512, 0, stream>>>(bsum, NB);
    k_scanC<<<NB, 256, 0, stream>>>(rowst, bsum, N);
    k_fill<<<EB, 256, 0, stream>>>(esrc, edst, dis, rowst, cnt, edge, E);

    // encoder: y2 = relu(prop(x)@W1+b1)@W2
    k_enc<<<CB, 256, 0, stream>>>(x, bufA, dis, rowst, deg, edge, W1, b1, W2, N);
    // z2 = prop(y2)+b2; out = z2@Wg1
    k_prop64<<<PB, 256, 0, stream>>>(bufA, bufB, dis, rowst, deg, edge, b2, 0, Wg1, nullptr, N);
    // z3 = relu(prop(.)+bg1); out = z3@Wg2
    k_prop64<<<PB, 256, 0, stream>>>(bufB, bufA, dis, rowst, deg, edge, bg1, 1, Wg2, nullptr, N);
    // z4 = relu(prop(.)+bg2); out = z4@Wg3
    k_prop64<<<PB, 256, 0, stream>>>(bufA, bufB, dis, rowst, deg, edge, bg2, 1, Wg3, nullptr, N);
    // z5 = relu(prop(.)+bg3)
    k_prop64<<<PB, 256, 0, stream>>>(bufB, bufA, dis, rowst, deg, edge, bg3, 1, nullptr, nullptr, N);
    // SGConv: 3 plain props, then prop + @Wsg + bsg
    k_prop64<<<PB, 256, 0, stream>>>(bufA, bufB, dis, rowst, deg, edge, nullptr, 0, nullptr, nullptr, N);
    k_prop64<<<PB, 256, 0, stream>>>(bufB, bufA, dis, rowst, deg, edge, nullptr, 0, nullptr, nullptr, N);
    k_prop64<<<PB, 256, 0, stream>>>(bufA, bufB, dis, rowst, deg, edge, nullptr, 0, nullptr, nullptr, N);
    k_prop64<<<PB, 256, 0, stream>>>(bufB, bufA, dis, rowst, deg, edge, nullptr, 0, Wsg, bsg, N);

    // pool + head
    k_pool_init<<<G_GRAPHS, 64, 0, stream>>>(gmax);
    k_pool<<<(N + 127) / 128, 256, 0, stream>>>(bufA, batch, gmax, N);
    k_head<<<1, 64, 0, stream>>>(gmax, Wf1, bf1, Wf2, bf2, Wc, bc, Wcb, bcb, (float*)d_out);
}